// Round 1
// baseline (302.976 us; speedup 1.0000x reference)
//
#include <hip/hip_runtime.h>

typedef __bf16 bf16_t;
typedef __bf16 bf16x8 __attribute__((ext_vector_type(8)));
typedef __bf16 bf16x4 __attribute__((ext_vector_type(4)));
typedef float f32x4 __attribute__((ext_vector_type(4)));

#define B_  2
#define N_  2048
#define D_  1024
#define H_  16
#define DH_ 64

// ---------------- RMSNorm: xn = x * (32/||x||) * gamma, bf16 out ----------------
__global__ __launch_bounds__(256) void k_rmsnorm(const float* __restrict__ x,
    const float* __restrict__ gamma, bf16_t* __restrict__ xn) {
  int row = blockIdx.x;                       // 4096 rows
  const float4* xr = (const float4*)(x + (size_t)row * D_);
  int tid = threadIdx.x;
  float4 v = xr[tid];
  float ss = v.x*v.x + v.y*v.y + v.z*v.z + v.w*v.w;
  #pragma unroll
  for (int off = 32; off > 0; off >>= 1) ss += __shfl_down(ss, off);
  __shared__ float red[4];
  if ((tid & 63) == 0) red[tid >> 6] = ss;
  __syncthreads();
  float scale = 32.0f * rsqrtf(red[0] + red[1] + red[2] + red[3]);
  float4 g = ((const float4*)gamma)[tid];
  bf16x4 o;
  o[0] = (bf16_t)(v.x * scale * g.x);
  o[1] = (bf16_t)(v.y * scale * g.y);
  o[2] = (bf16_t)(v.z * scale * g.z);
  o[3] = (bf16_t)(v.w * scale * g.w);
  *(bf16x4*)(xn + (size_t)row * D_ + tid * 4) = o;
}

// ---------------- transpose fp32 [R][C] -> bf16 [C][R] ----------------
__global__ __launch_bounds__(256) void k_transpose_cvt(const float* __restrict__ W,
    bf16_t* __restrict__ Wt, int R, int C) {
  __shared__ float tile[32][33];
  int c0 = blockIdx.x * 32, r0 = blockIdx.y * 32;
  int tx = threadIdx.x & 31, ty = threadIdx.x >> 5;
  #pragma unroll
  for (int i = 0; i < 4; ++i) {
    int r = ty + i * 8;
    tile[r][tx] = W[(size_t)(r0 + r) * C + c0 + tx];
  }
  __syncthreads();
  #pragma unroll
  for (int i = 0; i < 4; ++i) {
    int rr = ty + i * 8;
    Wt[(size_t)(c0 + rr) * R + r0 + tx] = (bf16_t)tile[tx][rr];
  }
}

// ---------------- GEMM: C[M][N] = A[M][K] * Bt[N][K]^T, bf16 MFMA ----------------
// 128x128 block tile, BK=32, 4 waves each computing 64x64 (4x4 grid of 16x16x32).
template<bool OUT_BF16>
__global__ __launch_bounds__(256) void k_gemm_bt(const bf16_t* __restrict__ A,
    const bf16_t* __restrict__ Bt, void* __restrict__ Cp, int M, int N, int K) {
  constexpr int BK = 32;
  __shared__ __align__(16) bf16_t As[128][BK + 8];   // +8 pad: 80B row stride
  __shared__ __align__(16) bf16_t Bs[128][BK + 8];
  int tid = threadIdx.x;
  int wave = tid >> 6, lane = tid & 63;
  int l16 = lane & 15, quad = lane >> 4;
  int bm = blockIdx.x * 128, bn = blockIdx.y * 128;
  int wm = (wave >> 1) * 64, wn = (wave & 1) * 64;
  f32x4 acc[4][4] = {};
  for (int k0 = 0; k0 < K; k0 += BK) {
    #pragma unroll
    for (int it = 0; it < 2; ++it) {
      int chunk = tid + 256 * it;            // 512 chunks of 8 bf16
      int r = chunk >> 2, c = (chunk & 3) * 8;
      *(bf16x8*)&As[r][c] = *(const bf16x8*)&A[(size_t)(bm + r) * K + k0 + c];
      *(bf16x8*)&Bs[r][c] = *(const bf16x8*)&Bt[(size_t)(bn + r) * K + k0 + c];
    }
    __syncthreads();
    bf16x8 af[4], bfr[4];
    #pragma unroll
    for (int t = 0; t < 4; ++t) {
      af[t]  = *(const bf16x8*)&As[wm + t * 16 + l16][quad * 8];
      bfr[t] = *(const bf16x8*)&Bs[wn + t * 16 + l16][quad * 8];
    }
    #pragma unroll
    for (int mt = 0; mt < 4; ++mt)
      #pragma unroll
      for (int nt = 0; nt < 4; ++nt)
        acc[mt][nt] = __builtin_amdgcn_mfma_f32_16x16x32_bf16(af[mt], bfr[nt], acc[mt][nt], 0, 0, 0);
    __syncthreads();
  }
  // C/D layout: col = lane&15, row = quad*4 + reg
  #pragma unroll
  for (int mt = 0; mt < 4; ++mt)
    #pragma unroll
    for (int nt = 0; nt < 4; ++nt)
      #pragma unroll
      for (int r = 0; r < 4; ++r) {
        int row = bm + wm + mt * 16 + quad * 4 + r;
        int col = bn + wn + nt * 16 + l16;
        float v = acc[mt][nt][r];
        if (OUT_BF16) ((bf16_t*)Cp)[(size_t)row * N + col] = (bf16_t)v;
        else          ((float*)Cp)[(size_t)row * N + col] = v;
      }
}

// ---------------- RoPE (interleaved) + scatter to Q/K/V [bh][n][64] bf16 ----------------
__global__ __launch_bounds__(256) void k_rope_scatter(const bf16_t* __restrict__ qkv,
    const float* __restrict__ freqs, bf16_t* __restrict__ Qb,
    bf16_t* __restrict__ Kb, bf16_t* __restrict__ Vb) {
  int row = blockIdx.x;                      // 0..4095 (b*2048+n)
  int b = row >> 11, n = row & 2047;
  const bf16_t* src = qkv + (size_t)row * 3072;
  for (int p = threadIdx.x; p < 1536; p += 256) {
    int c = p * 2;
    int t = c >> 10;                         // 0=q 1=k 2=v
    int w = c & 1023;
    int h = w >> 6, d = w & 63;
    float v0 = (float)src[c], v1 = (float)src[c + 1];
    if (t < 2) {
      float f = (float)n * freqs[d >> 1];
      float cs = cosf(f), sn = sinf(f);      // accurate libm: args up to ~2000 rad
      float r0 = v0 * cs - v1 * sn;
      float r1 = v1 * cs + v0 * sn;
      v0 = r0; v1 = r1;
    }
    bf16_t* dst = (t == 0) ? Qb : (t == 1) ? Kb : Vb;
    size_t base = (((size_t)(b * H_ + h)) * N_ + n) * DH_ + d;
    dst[base] = (bf16_t)v0;
    dst[base + 1] = (bf16_t)v1;
  }
}

// ---------------- gates: gsig[b*n][h] = sigmoid(xn . wg[:,h] + bg[h]) ----------------
__global__ __launch_bounds__(256) void k_gates(const bf16_t* __restrict__ xn,
    const float* __restrict__ wg, const float* __restrict__ bg,
    float* __restrict__ gsig) {
  int row = blockIdx.x;
  int tid = threadIdx.x;
  int h = tid & 15, seg = tid >> 4;
  const bf16_t* xr = xn + (size_t)row * D_;
  float part = 0.f;
  #pragma unroll 8
  for (int j = 0; j < 64; ++j) {
    int i = seg * 64 + j;
    part += (float)xr[i] * wg[i * 16 + h];
  }
  __shared__ float red[16][17];
  red[seg][h] = part;
  __syncthreads();
  if (tid < 16) {
    float s = bg[tid];
    #pragma unroll
    for (int sg = 0; sg < 16; ++sg) s += red[sg][tid];
    gsig[(size_t)row * 16 + tid] = 1.0f / (1.0f + __expf(-s));
  }
}

// ---------------- flash attention: 64 q-rows/block (16/wave), 64-key tiles ----------------
__global__ __launch_bounds__(256) void k_flash(const bf16_t* __restrict__ Qb,
    const bf16_t* __restrict__ Kb, const bf16_t* __restrict__ Vb,
    const float* __restrict__ gsig, bf16_t* __restrict__ Ao) {
  __shared__ __align__(16) bf16_t Ks[64][72];       // K tile [key][dh], +8 pad
  __shared__ __align__(16) bf16_t Vt[64][72];       // V^T tile [dh][key]
  __shared__ __align__(16) bf16_t Ps[4][16][72];    // per-wave P round-trip
  int bh = blockIdx.y;
  int b = bh >> 4, h = bh & 15;
  int q0 = blockIdx.x * 64;
  int tid = threadIdx.x, wave = tid >> 6, lane = tid & 63;
  int l16 = lane & 15, quad = lane >> 4;
  const bf16_t* Qh = Qb + (size_t)bh * N_ * DH_;
  const bf16_t* Kh = Kb + (size_t)bh * N_ * DH_;
  const bf16_t* Vh = Vb + (size_t)bh * N_ * DH_;
  // Q A-fragments: m = l16 -> row q0+wave*16+l16 ; k = quad*8+j
  int qrow = q0 + wave * 16 + l16;
  bf16x8 qf0 = *(const bf16x8*)&Qh[(size_t)qrow * DH_ + quad * 8];
  bf16x8 qf1 = *(const bf16x8*)&Qh[(size_t)qrow * DH_ + 32 + quad * 8];
  f32x4 accO[4] = {};
  float mrow[4] = {-1e30f, -1e30f, -1e30f, -1e30f};
  float lrow[4] = {0.f, 0.f, 0.f, 0.f};
  const float scale = 0.125f;                 // 1/sqrt(64)
  for (int k0 = 0; k0 < N_; k0 += 64) {
    #pragma unroll
    for (int it = 0; it < 2; ++it) {
      int chunk = tid + 256 * it;
      int rk = chunk >> 3, ck = (chunk & 7) * 8;
      *(bf16x8*)&Ks[rk][ck] = *(const bf16x8*)&Kh[(size_t)(k0 + rk) * DH_ + ck];
      // V: lane-per-row load, conflict-light transposed scatter into Vt
      int rv = chunk & 63, cv = (chunk >> 6) * 8;
      bf16x8 vv = *(const bf16x8*)&Vh[(size_t)(k0 + rv) * DH_ + cv];
      #pragma unroll
      for (int j = 0; j < 8; ++j) Vt[cv + j][rv] = vv[j];
    }
    __syncthreads();
    // S = Q K^T  (4 key sub-tiles of 16)
    f32x4 sac[4];
    #pragma unroll
    for (int kt = 0; kt < 4; ++kt) {
      bf16x8 kf0 = *(const bf16x8*)&Ks[kt * 16 + l16][quad * 8];
      bf16x8 kf1 = *(const bf16x8*)&Ks[kt * 16 + l16][32 + quad * 8];
      f32x4 z = {};
      z = __builtin_amdgcn_mfma_f32_16x16x32_bf16(qf0, kf0, z, 0, 0, 0);
      z = __builtin_amdgcn_mfma_f32_16x16x32_bf16(qf1, kf1, z, 0, 0, 0);
      sac[kt] = z;
    }
    // online softmax; lane holds rows quad*4+r, col kt*16+l16
    float mloc[4];
    #pragma unroll
    for (int r = 0; r < 4; ++r) {
      float a = fmaxf(fmaxf(sac[0][r], sac[1][r]), fmaxf(sac[2][r], sac[3][r]));
      mloc[r] = a * scale;
    }
    #pragma unroll
    for (int off = 1; off < 16; off <<= 1)
      #pragma unroll
      for (int r = 0; r < 4; ++r)
        mloc[r] = fmaxf(mloc[r], __shfl_xor(mloc[r], off));
    float alpha[4];
    #pragma unroll
    for (int r = 0; r < 4; ++r) {
      float mn = fmaxf(mrow[r], mloc[r]);
      alpha[r] = __expf(mrow[r] - mn);
      mrow[r] = mn;
    }
    float rsum[4] = {0.f, 0.f, 0.f, 0.f};
    #pragma unroll
    for (int kt = 0; kt < 4; ++kt)
      #pragma unroll
      for (int r = 0; r < 4; ++r) {
        float p = __expf(sac[kt][r] * scale - mrow[r]);
        rsum[r] += p;
        Ps[wave][quad * 4 + r][kt * 16 + l16] = (bf16_t)p;   // C-layout -> LDS
      }
    #pragma unroll
    for (int off = 1; off < 16; off <<= 1)
      #pragma unroll
      for (int r = 0; r < 4; ++r)
        rsum[r] += __shfl_xor(rsum[r], off);
    #pragma unroll
    for (int r = 0; r < 4; ++r) lrow[r] = lrow[r] * alpha[r] + rsum[r];
    #pragma unroll
    for (int dt = 0; dt < 4; ++dt)
      #pragma unroll
      for (int r = 0; r < 4; ++r) accO[dt][r] *= alpha[r];
    // P back as A-fragments (wave-local LDS round-trip)
    bf16x8 pf0 = *(const bf16x8*)&Ps[wave][l16][quad * 8];
    bf16x8 pf1 = *(const bf16x8*)&Ps[wave][l16][32 + quad * 8];
    #pragma unroll
    for (int dt = 0; dt < 4; ++dt) {
      bf16x8 vf0 = *(const bf16x8*)&Vt[dt * 16 + l16][quad * 8];
      bf16x8 vf1 = *(const bf16x8*)&Vt[dt * 16 + l16][32 + quad * 8];
      accO[dt] = __builtin_amdgcn_mfma_f32_16x16x32_bf16(pf0, vf0, accO[dt], 0, 0, 0);
      accO[dt] = __builtin_amdgcn_mfma_f32_16x16x32_bf16(pf1, vf1, accO[dt], 0, 0, 0);
    }
    __syncthreads();
  }
  // epilogue: /l, gate, write merged-head layout [b][n][h*64+dh]
  #pragma unroll
  for (int r = 0; r < 4; ++r) {
    int q = q0 + wave * 16 + quad * 4 + r;
    float g = gsig[((size_t)b * N_ + q) * H_ + h];
    float inv = g / lrow[r];
    #pragma unroll
    for (int dt = 0; dt < 4; ++dt) {
      float v = accO[dt][r] * inv;
      Ao[((size_t)b * N_ + q) * (H_ * DH_) + h * DH_ + dt * 16 + l16] = (bf16_t)v;
    }
  }
}

extern "C" void kernel_launch(void* const* d_in, const int* in_sizes, int n_in,
                              void* d_out, int out_size, void* d_ws, size_t ws_size,
                              hipStream_t stream) {
  (void)in_sizes; (void)n_in; (void)out_size; (void)ws_size;
  const float* x      = (const float*)d_in[0];
  const float* gamma  = (const float*)d_in[1];
  const float* w_qkv  = (const float*)d_in[2];
  const float* w_gate = (const float*)d_in[3];
  const float* b_gate = (const float*)d_in[4];
  const float* w_out  = (const float*)d_in[5];
  const float* freqs  = (const float*)d_in[6];
  float* out = (float*)d_out;
  char* ws = (char*)d_ws;
  // workspace layout (MB offsets), total 73 MB
  bf16_t* xn    = (bf16_t*)(ws);                          // 8 MB  [4096][1024]
  bf16_t* wqkvT = (bf16_t*)(ws + ((size_t)8  << 20));     // 6 MB  [3072][1024]
  bf16_t* woutT = (bf16_t*)(ws + ((size_t)14 << 20));     // 2 MB  [1024][1024]
  bf16_t* Qb    = (bf16_t*)(ws + ((size_t)16 << 20));     // 8 MB  [32][2048][64]
  bf16_t* Kb    = (bf16_t*)(ws + ((size_t)24 << 20));     // 8 MB
  bf16_t* Vb    = (bf16_t*)(ws + ((size_t)32 << 20));     // 8 MB
  float*  gsig  = (float*) (ws + ((size_t)40 << 20));     // 256 KB [4096][16]
  bf16_t* attn  = (bf16_t*)(ws + ((size_t)41 << 20));     // 8 MB  [4096][1024]
  bf16_t* qkvb  = (bf16_t*)(ws + ((size_t)49 << 20));     // 24 MB [4096][3072]

  k_transpose_cvt<<<dim3(3072 / 32, 1024 / 32), 256, 0, stream>>>(w_qkv, wqkvT, 1024, 3072);
  k_transpose_cvt<<<dim3(1024 / 32, 1024 / 32), 256, 0, stream>>>(w_out, woutT, 1024, 1024);
  k_rmsnorm<<<4096, 256, 0, stream>>>(x, gamma, xn);
  k_gemm_bt<true><<<dim3(32, 24), 256, 0, stream>>>(xn, wqkvT, (void*)qkvb, 4096, 3072, 1024);
  k_rope_scatter<<<4096, 256, 0, stream>>>(qkvb, freqs, Qb, Kb, Vb);
  k_gates<<<4096, 256, 0, stream>>>(xn, w_gate, b_gate, gsig);
  k_flash<<<dim3(32, 32), 256, 0, stream>>>(Qb, Kb, Vb, gsig, attn);
  k_gemm_bt<false><<<dim3(32, 8), 256, 0, stream>>>(attn, woutT, (void*)out, 4096, 1024, 1024);
}

// Round 2
// 252.994 us; speedup vs baseline: 1.1976x; 1.1976x over previous
//
#include <hip/hip_runtime.h>

typedef __bf16 bf16_t;
typedef __bf16 bf16x8 __attribute__((ext_vector_type(8)));
typedef __bf16 bf16x4 __attribute__((ext_vector_type(4)));
typedef float f32x4 __attribute__((ext_vector_type(4)));

#define B_  2
#define N_  2048
#define D_  1024
#define H_  16
#define DH_ 64

#define GLL16(g, l) __builtin_amdgcn_global_load_lds( \
    (const __attribute__((address_space(1))) void*)(g), \
    (__attribute__((address_space(3))) void*)(l), 16, 0, 0)

// ---------------- RMSNorm: xn = x * (32/||x||) * gamma, bf16 out ----------------
__global__ __launch_bounds__(256) void k_rmsnorm(const float* __restrict__ x,
    const float* __restrict__ gamma, bf16_t* __restrict__ xn) {
  int row = blockIdx.x;
  const float4* xr = (const float4*)(x + (size_t)row * D_);
  int tid = threadIdx.x;
  float4 v = xr[tid];
  float ss = v.x*v.x + v.y*v.y + v.z*v.z + v.w*v.w;
  #pragma unroll
  for (int off = 32; off > 0; off >>= 1) ss += __shfl_down(ss, off);
  __shared__ float red[4];
  if ((tid & 63) == 0) red[tid >> 6] = ss;
  __syncthreads();
  float scale = 32.0f * rsqrtf(red[0] + red[1] + red[2] + red[3]);
  float4 g = ((const float4*)gamma)[tid];
  bf16x4 o;
  o[0] = (bf16_t)(v.x * scale * g.x);
  o[1] = (bf16_t)(v.y * scale * g.y);
  o[2] = (bf16_t)(v.z * scale * g.z);
  o[3] = (bf16_t)(v.w * scale * g.w);
  *(bf16x4*)(xn + (size_t)row * D_ + tid * 4) = o;
}

// ---------------- transpose fp32 [R][C] -> bf16 [C][R] ----------------
__global__ __launch_bounds__(256) void k_transpose_cvt(const float* __restrict__ W,
    bf16_t* __restrict__ Wt, int R, int C) {
  __shared__ float tile[32][33];
  int c0 = blockIdx.x * 32, r0 = blockIdx.y * 32;
  int tx = threadIdx.x & 31, ty = threadIdx.x >> 5;
  #pragma unroll
  for (int i = 0; i < 4; ++i) {
    int r = ty + i * 8;
    tile[r][tx] = W[(size_t)(r0 + r) * C + c0 + tx];
  }
  __syncthreads();
  #pragma unroll
  for (int i = 0; i < 4; ++i) {
    int rr = ty + i * 8;
    Wt[(size_t)(c0 + rr) * R + r0 + tx] = (bf16_t)tile[tx][rr];
  }
}

// ---------------- GEMM: C[M][N] = A[M][K] * Bt[N][K]^T, m97-style ----------------
// 128x128 tile, BK=32, global_load_lds width-16, unpadded stride-32 LDS.
template<bool OUT_BF16>
__global__ __launch_bounds__(256) void k_gemm_bt(const bf16_t* __restrict__ A,
    const bf16_t* __restrict__ Bt, void* __restrict__ Cp, int M, int N, int K) {
  constexpr int BK = 32;
  __shared__ __align__(16) bf16_t As[128 * BK];
  __shared__ __align__(16) bf16_t Bs[128 * BK];
  int tid = threadIdx.x, wave = tid >> 6, lane = tid & 63;
  int l16 = lane & 15, quad = lane >> 4;
  int bm = blockIdx.x * 128, bn = blockIdx.y * 128;
  int wm = (wave >> 1) * 64, wn = (wave & 1) * 64;
  // staging: wave w covers LDS rows [w*32, w*32+32); 2 instrs of 16 rows each
  int srow = wave * 32 + (lane >> 2);
  int scol = (lane & 3) * 8;
  const bf16_t* gA0 = &A [(size_t)(bm + srow)      * K + scol];
  const bf16_t* gA1 = &A [(size_t)(bm + srow + 16) * K + scol];
  const bf16_t* gB0 = &Bt[(size_t)(bn + srow)      * K + scol];
  const bf16_t* gB1 = &Bt[(size_t)(bn + srow + 16) * K + scol];
  bf16_t* lA0 = &As[(wave * 32)      * BK];   // wave-uniform bases
  bf16_t* lA1 = &As[(wave * 32 + 16) * BK];
  bf16_t* lB0 = &Bs[(wave * 32)      * BK];
  bf16_t* lB1 = &Bs[(wave * 32 + 16) * BK];
  f32x4 acc[4][4] = {};
  for (int k0 = 0; k0 < K; k0 += BK) {
    GLL16(gA0 + k0, lA0);
    GLL16(gA1 + k0, lA1);
    GLL16(gB0 + k0, lB0);
    GLL16(gB1 + k0, lB1);
    __syncthreads();
    bf16x8 af[4], bfr[4];
    #pragma unroll
    for (int t = 0; t < 4; ++t) {
      af[t]  = *(const bf16x8*)&As[(wm + t * 16 + l16) * BK + quad * 8];
      bfr[t] = *(const bf16x8*)&Bs[(wn + t * 16 + l16) * BK + quad * 8];
    }
    #pragma unroll
    for (int mt = 0; mt < 4; ++mt)
      #pragma unroll
      for (int nt = 0; nt < 4; ++nt)
        acc[mt][nt] = __builtin_amdgcn_mfma_f32_16x16x32_bf16(af[mt], bfr[nt], acc[mt][nt], 0, 0, 0);
    __syncthreads();
  }
  #pragma unroll
  for (int mt = 0; mt < 4; ++mt)
    #pragma unroll
    for (int nt = 0; nt < 4; ++nt)
      #pragma unroll
      for (int r = 0; r < 4; ++r) {
        int row = bm + wm + mt * 16 + quad * 4 + r;
        int col = bn + wn + nt * 16 + l16;
        float v = acc[mt][nt][r];
        if (OUT_BF16) ((bf16_t*)Cp)[(size_t)row * N + col] = (bf16_t)v;
        else          ((float*)Cp)[(size_t)row * N + col] = v;
      }
}

// ---------------- RoPE for Q,K (LDS-cached trig), Q pre-scaled by 1/8 ----------------
__global__ __launch_bounds__(256) void k_rope(const bf16_t* __restrict__ qkvb,
    const float* __restrict__ freqs, bf16_t* __restrict__ Qb, bf16_t* __restrict__ Kb) {
  int row = blockIdx.x, b = row >> 11, n = row & 2047;
  __shared__ float cs[32], sn[32];
  int tid = threadIdx.x;
  if (tid < 32) { float f = (float)n * freqs[tid]; cs[tid] = cosf(f); sn[tid] = sinf(f); }
  __syncthreads();
  const bf16_t* src = qkvb + (size_t)row * 3072;
  #pragma unroll
  for (int it = 0; it < 2; ++it) {
    int p = tid + 256 * it;            // 0..511 pairs
    int h = p >> 5, j = p & 31;
    size_t dst = ((size_t)(b * H_ + h) * N_ + n) * DH_ + 2 * j;
    float c = cs[j], s = sn[j];
    {
      float v0 = (float)src[h * 64 + 2 * j], v1 = (float)src[h * 64 + 2 * j + 1];
      union { bf16_t q[2]; unsigned u; } pk;
      pk.q[0] = (bf16_t)((v0 * c - v1 * s) * 0.125f);
      pk.q[1] = (bf16_t)((v1 * c + v0 * s) * 0.125f);
      *(unsigned*)&Qb[dst] = pk.u;
    }
    {
      float v0 = (float)src[1024 + h * 64 + 2 * j], v1 = (float)src[1024 + h * 64 + 2 * j + 1];
      union { bf16_t q[2]; unsigned u; } pk;
      pk.q[0] = (bf16_t)(v0 * c - v1 * s);
      pk.q[1] = (bf16_t)(v1 * c + v0 * s);
      *(unsigned*)&Kb[dst] = pk.u;
    }
  }
}

// ---------------- V transpose: qkvb[., 2048+h*64+d] -> Vb[bh][d][n] ----------------
__global__ __launch_bounds__(256) void k_vtrans(const bf16_t* __restrict__ qkvb,
    bf16_t* __restrict__ Vb) {
  __shared__ bf16_t Vs[64][72];
  int bh = blockIdx.x, nt = blockIdx.y;
  int b = bh >> 4, h = bh & 15;
  int n0 = nt * 64;
  int tid = threadIdx.x;
  #pragma unroll
  for (int it = 0; it < 2; ++it) {
    int chunk = tid + 256 * it;
    int nl = chunk >> 3, c = (chunk & 7) * 8;
    *(bf16x8*)&Vs[nl][c] =
        *(const bf16x8*)&qkvb[(size_t)(b * N_ + n0 + nl) * 3072 + 2048 + h * 64 + c];
  }
  __syncthreads();
  #pragma unroll
  for (int it = 0; it < 2; ++it) {
    int chunk = tid + 256 * it;
    int d = chunk >> 3, nc = (chunk & 7) * 8;
    bf16x8 o;
    #pragma unroll
    for (int jj = 0; jj < 8; ++jj) o[jj] = Vs[nc + jj][d];
    *(bf16x8*)&Vb[((size_t)bh * DH_ + d) * N_ + n0 + nc] = o;
  }
}

// ---------------- gates: gsig[row][h] = sigmoid(xn . wg[:,h] + bg[h]) ----------------
__global__ __launch_bounds__(256) void k_gates(const bf16_t* __restrict__ xn,
    const float* __restrict__ wg, const float* __restrict__ bg,
    float* __restrict__ gsig) {
  int row = blockIdx.x;
  int tid = threadIdx.x;
  int h = tid & 15, seg = tid >> 4;
  const bf16_t* xr = xn + (size_t)row * D_;
  float part = 0.f;
  #pragma unroll 8
  for (int j = 0; j < 64; ++j) {
    int i = seg * 64 + j;
    part += (float)xr[i] * wg[i * 16 + h];
  }
  __shared__ float red[16][17];
  red[seg][h] = part;
  __syncthreads();
  if (tid < 16) {
    float s = bg[tid];
    #pragma unroll
    for (int sg = 0; sg < 16; ++sg) s += red[sg][tid];
    gsig[(size_t)row * 16 + tid] = 1.0f / (1.0f + __expf(-s));
  }
}

// ---------------- flash attention: S^T form, fixed-max softmax, 32 q/wave ----------------
__global__ __launch_bounds__(256) void k_flash(const bf16_t* __restrict__ Qb,
    const bf16_t* __restrict__ Kb, const bf16_t* __restrict__ Vb,
    const float* __restrict__ gsig, bf16_t* __restrict__ Ao) {
  __shared__ __align__(16) bf16_t Ks[64 * 72];       // [key][dh], stride 72
  __shared__ __align__(16) bf16_t Vt[64 * 72];       // [dh][key], stride 72
  __shared__ __align__(16) bf16_t Ps[4][32 * 72];    // per-wave [q][key], stride 72
  int bh = blockIdx.y, b = bh >> 4, h = bh & 15;
  int tid = threadIdx.x, wave = tid >> 6, lane = tid & 63;
  int l16 = lane & 15, quad = lane >> 4;
  int qw = blockIdx.x * 128 + wave * 32;
  const bf16_t* Qh = Qb + (size_t)bh * N_ * DH_;
  const bf16_t* Kh = Kb + (size_t)bh * N_ * DH_;
  const bf16_t* Vh = Vb + (size_t)bh * DH_ * N_;     // [64][2048]
  bf16_t* Pw = Ps[wave];
  // Q fragments (B-operand): n = q row, k = d. Q pre-scaled by 1/8.
  bf16x8 qf[2][2];
  #pragma unroll
  for (int qt = 0; qt < 2; ++qt)
    #pragma unroll
    for (int hf = 0; hf < 2; ++hf)
      qf[qt][hf] = *(const bf16x8*)&Qh[(size_t)(qw + qt * 16 + l16) * DH_ + hf * 32 + quad * 8];
  f32x4 accO[2][4] = {};
  float lsum[2] = {0.f, 0.f};
  int sk = tid >> 3;                 // 0..31
  int sc = (tid & 7) * 8;
  for (int k0 = 0; k0 < N_; k0 += 64) {
    *(bf16x8*)&Ks[sk * 72 + sc]        = *(const bf16x8*)&Kh[(size_t)(k0 + sk) * DH_ + sc];
    *(bf16x8*)&Ks[(sk + 32) * 72 + sc] = *(const bf16x8*)&Kh[(size_t)(k0 + sk + 32) * DH_ + sc];
    *(bf16x8*)&Vt[sk * 72 + sc]        = *(const bf16x8*)&Vh[(size_t)sk * N_ + k0 + sc];
    *(bf16x8*)&Vt[(sk + 32) * 72 + sc] = *(const bf16x8*)&Vh[(size_t)(sk + 32) * N_ + k0 + sc];
    __syncthreads();
    // S^T = K . Q^T  -> C[key][q]; lane holds key=kt*16+quad*4+r, q=qt*16+l16
    f32x4 st[4][2];
    #pragma unroll
    for (int kt = 0; kt < 4; ++kt) {
      bf16x8 kf0 = *(const bf16x8*)&Ks[(kt * 16 + l16) * 72 + quad * 8];
      bf16x8 kf1 = *(const bf16x8*)&Ks[(kt * 16 + l16) * 72 + 32 + quad * 8];
      #pragma unroll
      for (int qt = 0; qt < 2; ++qt) {
        f32x4 z = {};
        z = __builtin_amdgcn_mfma_f32_16x16x32_bf16(kf0, qf[qt][0], z, 0, 0, 0);
        z = __builtin_amdgcn_mfma_f32_16x16x32_bf16(kf1, qf[qt][1], z, 0, 0, 0);
        st[kt][qt] = z;
      }
    }
    // fixed-max softmax: p = exp(s - 8); b64 packed store straight into A-layout
    #pragma unroll
    for (int qt = 0; qt < 2; ++qt)
      #pragma unroll
      for (int kt = 0; kt < 4; ++kt) {
        bf16x4 pk;
        #pragma unroll
        for (int r = 0; r < 4; ++r) {
          float p = __expf(st[kt][qt][r] - 8.0f);
          lsum[qt] += p;
          pk[r] = (bf16_t)p;
        }
        *(bf16x4*)&Pw[(qt * 16 + l16) * 72 + kt * 16 + quad * 4] = pk;
      }
    // P fragments (A-operand) + PV
    bf16x8 pf[2][2];
    #pragma unroll
    for (int qt = 0; qt < 2; ++qt)
      #pragma unroll
      for (int hf = 0; hf < 2; ++hf)
        pf[qt][hf] = *(const bf16x8*)&Pw[(qt * 16 + l16) * 72 + hf * 32 + quad * 8];
    #pragma unroll
    for (int dt = 0; dt < 4; ++dt)
      #pragma unroll
      for (int hf = 0; hf < 2; ++hf) {
        bf16x8 vf = *(const bf16x8*)&Vt[(dt * 16 + l16) * 72 + hf * 32 + quad * 8];
        #pragma unroll
        for (int qt = 0; qt < 2; ++qt)
          accO[qt][dt] = __builtin_amdgcn_mfma_f32_16x16x32_bf16(pf[qt][hf], vf, accO[qt][dt], 0, 0, 0);
      }
    __syncthreads();
  }
  // row sums: reduce over quads (lane's lsum covers keys of its quad for q=qt*16+l16)
  float lfull[2];
  #pragma unroll
  for (int qt = 0; qt < 2; ++qt) {
    float s = lsum[qt];
    s += __shfl_xor(s, 16);
    s += __shfl_xor(s, 32);
    lfull[qt] = s;
  }
  // epilogue: O in C layout (q = qt*16+quad*4+r, d = dt*16+l16)
  #pragma unroll
  for (int qt = 0; qt < 2; ++qt)
    #pragma unroll
    for (int r = 0; r < 4; ++r) {
      int qs = quad * 4 + r;
      float l_e = __shfl(lfull[qt], qs);     // lane qs holds l for q=qt*16+qs
      int q = qw + qt * 16 + qs;
      float g = gsig[((size_t)b * N_ + q) * H_ + h];
      float ginv = g / l_e;
      #pragma unroll
      for (int dt = 0; dt < 4; ++dt)
        Ao[((size_t)b * N_ + q) * (H_ * DH_) + h * DH_ + dt * 16 + l16] =
            (bf16_t)(accO[qt][dt][r] * ginv);
    }
}

extern "C" void kernel_launch(void* const* d_in, const int* in_sizes, int n_in,
                              void* d_out, int out_size, void* d_ws, size_t ws_size,
                              hipStream_t stream) {
  (void)in_sizes; (void)n_in; (void)out_size; (void)ws_size;
  const float* x      = (const float*)d_in[0];
  const float* gamma  = (const float*)d_in[1];
  const float* w_qkv  = (const float*)d_in[2];
  const float* w_gate = (const float*)d_in[3];
  const float* b_gate = (const float*)d_in[4];
  const float* w_out  = (const float*)d_in[5];
  const float* freqs  = (const float*)d_in[6];
  float* out = (float*)d_out;
  char* ws = (char*)d_ws;
  bf16_t* xn    = (bf16_t*)(ws);                          // 8 MB
  bf16_t* wqkvT = (bf16_t*)(ws + ((size_t)8  << 20));     // 6 MB
  bf16_t* woutT = (bf16_t*)(ws + ((size_t)14 << 20));     // 2 MB
  bf16_t* Qb    = (bf16_t*)(ws + ((size_t)16 << 20));     // 8 MB [bh][n][64]
  bf16_t* Kb    = (bf16_t*)(ws + ((size_t)24 << 20));     // 8 MB [bh][n][64]
  bf16_t* Vb    = (bf16_t*)(ws + ((size_t)32 << 20));     // 8 MB [bh][64][n]
  float*  gsig  = (float*) (ws + ((size_t)40 << 20));     // 256 KB
  bf16_t* attn  = (bf16_t*)(ws + ((size_t)41 << 20));     // 8 MB
  bf16_t* qkvb  = (bf16_t*)(ws + ((size_t)49 << 20));     // 24 MB

  k_transpose_cvt<<<dim3(3072 / 32, 1024 / 32), 256, 0, stream>>>(w_qkv, wqkvT, 1024, 3072);
  k_transpose_cvt<<<dim3(1024 / 32, 1024 / 32), 256, 0, stream>>>(w_out, woutT, 1024, 1024);
  k_rmsnorm<<<4096, 256, 0, stream>>>(x, gamma, xn);
  k_gemm_bt<true><<<dim3(32, 24), 256, 0, stream>>>(xn, wqkvT, (void*)qkvb, 4096, 3072, 1024);
  k_rope<<<4096, 256, 0, stream>>>(qkvb, freqs, Qb, Kb);
  k_vtrans<<<dim3(32, 32), 256, 0, stream>>>(qkvb, Vb);
  k_gates<<<4096, 256, 0, stream>>>(xn, w_gate, b_gate, gsig);
  k_flash<<<dim3(16, 32), 256, 0, stream>>>(Qb, Kb, Vb, gsig, attn);
  k_gemm_bt<false><<<dim3(32, 8), 256, 0, stream>>>(attn, woutT, (void*)out, 4096, 1024, 1024);
}